// Round 1
// baseline (160.416 us; speedup 1.0000x reference)
//
#include <hip/hip_runtime.h>

#define U 128
#define NSEG 32
#define NPATH 512
#define ROW (NSEG * U)   // 4096 floats per batch row

// Workspace layout: path metadata sorted (grouped) by pout, order-preserving.
struct PathCSR {
    int   p0[NPATH];
    int   p1[NPATH];
    float c[NPATH];
    int   segstart[NSEG + 1];
};

// One wave: lane s (< NSEG) owns output segment s; counts, prefix-sums via
// shuffle, then scatters its paths in original-k order (deterministic).
__global__ void build_csr(const float* __restrict__ coeffs,
                          const int* __restrict__ p0,
                          const int* __restrict__ p1,
                          const int* __restrict__ pout,
                          PathCSR* __restrict__ ws) {
    const int s = threadIdx.x;            // 0..63, only 0..31 active for work
    int cnt = 0;
    if (s < NSEG) {
        for (int k = 0; k < NPATH; ++k) cnt += (pout[k] == s) ? 1 : 0;
    }
    // inclusive scan across the 64-lane wave (lanes >= NSEG hold 0)
    int inc = cnt;
    #pragma unroll
    for (int d = 1; d < 64; d <<= 1) {
        int t = __shfl_up(inc, d, 64);
        if ((threadIdx.x & 63) >= d) inc += t;
    }
    const int excl = inc - cnt;
    if (s < NSEG) {
        ws->segstart[s] = excl;
        if (s == NSEG - 1) ws->segstart[NSEG] = excl + cnt;
        int w = excl;
        for (int k = 0; k < NPATH; ++k) {
            if (pout[k] == s) {
                ws->p0[w] = p0[k];
                ws->p1[w] = p1[k];
                ws->c[w]  = coeffs[k];
                ++w;
            }
        }
    }
}

// One block per batch row. Stage x0/x1 row in LDS (32 KiB). 2 waves split the
// segment list at a path-count-balanced boundary. Lane owns a float2 of u.
// Output accumulates in registers; one coalesced float2 store per segment.
__global__ __launch_bounds__(128) void tp_kernel(const float* __restrict__ x0,
                                                 const float* __restrict__ x1,
                                                 const PathCSR* __restrict__ ws,
                                                 float* __restrict__ out) {
    __shared__ float lds0[ROW];
    __shared__ float lds1[ROW];

    const int b   = blockIdx.x;
    const int tid = threadIdx.x;

    // --- stage full row (coalesced float4) ---
    const float4* g0 = reinterpret_cast<const float4*>(x0 + (size_t)b * ROW);
    const float4* g1 = reinterpret_cast<const float4*>(x1 + (size_t)b * ROW);
    float4* s0v = reinterpret_cast<float4*>(lds0);
    float4* s1v = reinterpret_cast<float4*>(lds1);
    #pragma unroll
    for (int j = 0; j < (ROW / 4) / 128; ++j) {   // 8 iters
        s0v[tid + j * 128] = g0[tid + j * 128];
        s1v[tid + j * 128] = g1[tid + j * 128];
    }
    __syncthreads();

    const int wave = tid >> 6;
    const int lane = tid & 63;

    // balanced split point: segment boundary whose segstart is closest to P/2
    int split = NSEG / 2;
    {
        int best = 1 << 30;
        for (int s = 0; s <= NSEG; ++s) {
            int d = ws->segstart[s] - (NPATH / 2);
            if (d < 0) d = -d;
            if (d < best) { best = d; split = s; }
        }
    }
    const int sBeg = (wave == 0) ? 0 : split;
    const int sEnd = (wave == 0) ? split : NSEG;

    const float2* s0p = reinterpret_cast<const float2*>(lds0);
    const float2* s1p = reinterpret_cast<const float2*>(lds1);
    float* outrow = out + (size_t)b * ROW;

    for (int s = sBeg; s < sEnd; ++s) {
        float accx = 0.f, accy = 0.f;
        const int jb = ws->segstart[s];
        const int je = ws->segstart[s + 1];
        for (int j = jb; j < je; ++j) {
            const int   a0 = ws->p0[j];
            const int   a1 = ws->p1[j];
            const float c  = ws->c[j];
            const float2 v0 = s0p[a0 * (U / 2) + lane];
            const float2 v1 = s1p[a1 * (U / 2) + lane];
            accx += c * v0.x * v1.x;
            accy += c * v0.y * v1.y;
        }
        float2 o; o.x = accx; o.y = accy;
        reinterpret_cast<float2*>(outrow + s * U)[lane] = o;
    }
}

extern "C" void kernel_launch(void* const* d_in, const int* in_sizes, int n_in,
                              void* d_out, int out_size, void* d_ws, size_t ws_size,
                              hipStream_t stream) {
    const float* x0     = (const float*)d_in[0];
    const float* x1     = (const float*)d_in[1];
    const float* coeffs = (const float*)d_in[2];
    const int*   p0     = (const int*)d_in[3];
    const int*   p1     = (const int*)d_in[4];
    const int*   pout   = (const int*)d_in[5];
    float* out = (float*)d_out;
    PathCSR* ws = (PathCSR*)d_ws;

    build_csr<<<1, 64, 0, stream>>>(coeffs, p0, p1, pout, ws);
    tp_kernel<<<2048, 128, 0, stream>>>(x0, x1, ws, out);
}

// Round 2
// 92.718 us; speedup vs baseline: 1.7301x; 1.7301x over previous
//
#include <hip/hip_runtime.h>

#define U 128
#define NSEG 32
#define NPATH 512
#define ROW (NSEG * U)   // 4096 floats per batch row
#define NW 4             // waves per tp block

// Path metadata, grouped (order-preserving) by pout.
struct Meta { unsigned pp; float c; };   // pp = p0 | (p1 << 16)
struct WS {
    Meta meta[NPATH];        // 4096 B
    int  segstart[NSEG + 1]; // CSR boundaries into meta[]
    int  wsplit[NW + 1];     // segment-boundary split per wave, balanced by path count
};

// One block, 64 threads. Stage all path arrays in LDS, then lane s (<NSEG)
// counts its segment, wave-scan for offsets, scatter packed meta in original-k
// order (deterministic). Also computes balanced 4-way split boundaries.
__global__ __launch_bounds__(64) void build_csr(const float* __restrict__ coeffs,
                                                const int* __restrict__ p0,
                                                const int* __restrict__ p1,
                                                const int* __restrict__ pout,
                                                WS* __restrict__ ws) {
    __shared__ int   sp0[NPATH], sp1[NPATH], spo[NPATH];
    __shared__ float sc[NPATH];
    const int t = threadIdx.x;

    for (int j = t; j < NPATH; j += 64) {
        sp0[j] = p0[j]; sp1[j] = p1[j]; spo[j] = pout[j]; sc[j] = coeffs[j];
    }
    __syncthreads();

    const int s = t;
    int cnt = 0;
    if (s < NSEG) {
        for (int k = 0; k < NPATH; ++k) cnt += (spo[k] == s) ? 1 : 0;
    }
    // inclusive wave scan (lanes >= NSEG contribute 0)
    int inc = cnt;
    #pragma unroll
    for (int d = 1; d < 64; d <<= 1) {
        int tt = __shfl_up(inc, d, 64);
        if (t >= d) inc += tt;
    }
    const int excl = inc - cnt;   // lane s: segstart[s]; lanes >= NSEG hold total

    if (s < NSEG) {
        ws->segstart[s] = excl;
        if (s == NSEG - 1) ws->segstart[NSEG] = excl + cnt;
        int w = excl;
        for (int k = 0; k < NPATH; ++k) {
            if (spo[k] == s) {
                Meta m;
                m.pp = (unsigned)sp0[k] | ((unsigned)sp1[k] << 16);
                m.c  = sc[k];
                ws->meta[w] = m;
                ++w;
            }
        }
    }

    // Balanced split boundaries: for target w*NPATH/NW, pick the segment
    // boundary whose segstart is closest (monotone in target -> valid partition).
    #pragma unroll
    for (int w = 1; w < NW; ++w) {
        const int target = (NPATH * w) / NW;
        int d = excl - target; if (d < 0) d = -d;
        int key = (t <= NSEG) ? (d * 64 + t) : 0x7fffffff;
        #pragma unroll
        for (int m = 32; m >= 1; m >>= 1) {
            int o = __shfl_xor(key, m, 64);
            key = (o < key) ? o : key;
        }
        if (t == 0) ws->wsplit[w] = key & 63;
    }
    if (t == 0) { ws->wsplit[0] = 0; ws->wsplit[NW] = NSEG; }
}

// One block (256 threads, 4 waves) per batch row. Rows + metadata staged in
// LDS; each wave owns a contiguous range of output segments; accumulation in
// registers, 2-path unroll for ILP; coalesced float2 stores.
__global__ __launch_bounds__(256) void tp_kernel(const float* __restrict__ x0,
                                                 const float* __restrict__ x1,
                                                 const WS* __restrict__ ws,
                                                 float* __restrict__ out) {
    __shared__ float lds0[ROW];
    __shared__ float lds1[ROW];
    __shared__ Meta  smeta[NPATH];
    __shared__ int   sseg[NSEG + 1];
    __shared__ int   ssplit[NW + 1];

    const int b   = blockIdx.x;
    const int tid = threadIdx.x;

    // stage rows (coalesced float4)
    const float4* g0 = reinterpret_cast<const float4*>(x0 + (size_t)b * ROW);
    const float4* g1 = reinterpret_cast<const float4*>(x1 + (size_t)b * ROW);
    float4* s0v = reinterpret_cast<float4*>(lds0);
    float4* s1v = reinterpret_cast<float4*>(lds1);
    #pragma unroll
    for (int j = 0; j < (ROW / 4) / 256; ++j) {   // 4 iters each
        s0v[tid + j * 256] = g0[tid + j * 256];
        s1v[tid + j * 256] = g1[tid + j * 256];
    }
    // stage metadata (512 * 8 B = 4 KiB -> one float4 per thread)
    reinterpret_cast<float4*>(smeta)[tid] =
        reinterpret_cast<const float4*>(ws->meta)[tid];
    if (tid < NSEG + 1) sseg[tid] = ws->segstart[tid];
    if (tid < NW + 1)   ssplit[tid] = ws->wsplit[tid];
    __syncthreads();

    const int wave = tid >> 6;
    const int lane = tid & 63;
    const int sBeg = ssplit[wave];
    const int sEnd = ssplit[wave + 1];

    const float2* s0p = reinterpret_cast<const float2*>(lds0);
    const float2* s1p = reinterpret_cast<const float2*>(lds1);
    float* outrow = out + (size_t)b * ROW;

    for (int s = sBeg; s < sEnd; ++s) {
        const int jb = sseg[s];
        const int je = sseg[s + 1];
        float a0x = 0.f, a0y = 0.f, a1x = 0.f, a1y = 0.f;
        int j = jb;
        for (; j + 1 < je; j += 2) {
            const Meta m0 = smeta[j];
            const Meta m1 = smeta[j + 1];
            const float2 u0 = s0p[(m0.pp & 0xffffu) * (U / 2) + lane];
            const float2 v0 = s0p[0];  // placeholder to keep symmetry? (removed below)
            (void)v0;
            const float2 w0 = s1p[(m0.pp >> 16) * (U / 2) + lane];
            const float2 u1 = s0p[(m1.pp & 0xffffu) * (U / 2) + lane];
            const float2 w1 = s1p[(m1.pp >> 16) * (U / 2) + lane];
            a0x += m0.c * u0.x * w0.x;
            a0y += m0.c * u0.y * w0.y;
            a1x += m1.c * u1.x * w1.x;
            a1y += m1.c * u1.y * w1.y;
        }
        if (j < je) {
            const Meta m = smeta[j];
            const float2 u = s0p[(m.pp & 0xffffu) * (U / 2) + lane];
            const float2 w = s1p[(m.pp >> 16) * (U / 2) + lane];
            a0x += m.c * u.x * w.x;
            a0y += m.c * u.y * w.y;
        }
        float2 o; o.x = a0x + a1x; o.y = a0y + a1y;
        reinterpret_cast<float2*>(outrow + s * U)[lane] = o;
    }
}

extern "C" void kernel_launch(void* const* d_in, const int* in_sizes, int n_in,
                              void* d_out, int out_size, void* d_ws, size_t ws_size,
                              hipStream_t stream) {
    const float* x0     = (const float*)d_in[0];
    const float* x1     = (const float*)d_in[1];
    const float* coeffs = (const float*)d_in[2];
    const int*   p0     = (const int*)d_in[3];
    const int*   p1     = (const int*)d_in[4];
    const int*   pout   = (const int*)d_in[5];
    float* out = (float*)d_out;
    WS* ws = (WS*)d_ws;

    build_csr<<<1, 64, 0, stream>>>(coeffs, p0, p1, pout, ws);
    tp_kernel<<<2048, 256, 0, stream>>>(x0, x1, ws, out);
}

// Round 3
// 38.069 us; speedup vs baseline: 4.2138x; 2.4355x over previous
//
#include <hip/hip_runtime.h>

#define U 128
#define NSEG 32
#define NPATH 512
#define ROW (NSEG * U)   // 4096 floats per batch row
#define NW 8             // waves per tp block (512 threads)

// Path metadata, grouped (order-preserving) by pout.
struct Meta { unsigned pp; float c; };   // pp = p0 | (p1 << 16)
struct WS {
    Meta meta[NPATH];        // 4096 B
    int  segstart[NSEG + 1]; // CSR boundaries into meta[]
    int  wsplit[NW + 1];     // segment-boundary split per wave
};

// One block, 512 threads: thread k owns path k. Deterministic parallel
// counting-sort by pout (original-k order preserved within each segment).
__global__ __launch_bounds__(512) void build_csr(const float* __restrict__ coeffs,
                                                 const int* __restrict__ p0,
                                                 const int* __restrict__ p1,
                                                 const int* __restrict__ pout,
                                                 WS* __restrict__ ws) {
    __shared__ int wcnt[NPATH / 64][NSEG];   // per-wave per-segment counts
    __shared__ int wpre[NPATH / 64][NSEG];   // prefix over earlier waves
    __shared__ int sseg[NSEG + 1];

    const int k    = threadIdx.x;
    const int lane = k & 63;
    const int wave = k >> 6;

    const int   po = pout[k];
    const int   a0 = p0[k];
    const int   a1 = p1[k];
    const float c  = coeffs[k];

    // rank within wave + per-wave counts, via 32 ballots
    const unsigned long long lt = (1ull << lane) - 1ull;
    int rank = 0;
    #pragma unroll
    for (int s = 0; s < NSEG; ++s) {
        unsigned long long m = __ballot(po == s);
        if (po == s)  rank = (int)__popcll(m & lt);
        if (lane == s) wcnt[wave][s] = (int)__popcll(m);
    }
    __syncthreads();

    // per-segment: prefix over waves + totals (threads 0..31)
    __shared__ int stot[NSEG];
    if (k < NSEG) {
        int tot = 0;
        #pragma unroll
        for (int w = 0; w < NPATH / 64; ++w) { wpre[w][k] = tot; tot += wcnt[w][k]; }
        stot[k] = tot;
    }
    __syncthreads();

    // exclusive scan of totals over segments (wave 0)
    if (k < 64) {
        int v = (k < NSEG) ? stot[k] : 0;
        int inc = v;
        #pragma unroll
        for (int d = 1; d < 64; d <<= 1) {
            int t = __shfl_up(inc, d, 64);
            if (k >= d) inc += t;
        }
        int excl = inc - v;
        if (k < NSEG) sseg[k] = excl;
        if (k == NSEG - 1) sseg[NSEG] = excl + v;
    }
    __syncthreads();

    // scatter (deterministic position)
    {
        Meta m;
        m.pp = (unsigned)a0 | ((unsigned)a1 << 16);
        m.c  = c;
        ws->meta[sseg[po] + wpre[wave][po] + rank] = m;
    }
    if (k <= NSEG) ws->segstart[k] = sseg[k];

    // balanced NW-way split boundaries (wave 0); argmin |segstart - target|
    if (k < 64) {
        #pragma unroll
        for (int w = 1; w < NW; ++w) {
            const int target = (NPATH * w) / NW;
            int key;
            if (k <= NSEG) {
                int d = sseg[k] - target; if (d < 0) d = -d;
                key = (d << 6) | k;
            } else key = 0x7fffffff;
            #pragma unroll
            for (int m = 32; m >= 1; m >>= 1) {
                int o = __shfl_xor(key, m, 64);
                key = (o < key) ? o : key;
            }
            if (k == 0) ws->wsplit[w] = key & 63;
        }
        if (k == 0) { ws->wsplit[0] = 0; ws->wsplit[NW] = NSEG; }
    }
}

// One block (512 threads, 8 waves) per batch row.
__global__ __launch_bounds__(512) void tp_kernel(const float* __restrict__ x0,
                                                 const float* __restrict__ x1,
                                                 const WS* __restrict__ ws,
                                                 float* __restrict__ out) {
    __shared__ float lds0[ROW];
    __shared__ float lds1[ROW];
    __shared__ Meta  smeta[NPATH];
    __shared__ int   sseg[NSEG + 1];
    __shared__ int   ssplit[NW + 1];

    const int b   = blockIdx.x;
    const int tid = threadIdx.x;

    const float4* g0 = reinterpret_cast<const float4*>(x0 + (size_t)b * ROW);
    const float4* g1 = reinterpret_cast<const float4*>(x1 + (size_t)b * ROW);
    float4* s0v = reinterpret_cast<float4*>(lds0);
    float4* s1v = reinterpret_cast<float4*>(lds1);
    #pragma unroll
    for (int j = 0; j < (ROW / 4) / 512; ++j) {   // 2 iters each
        s0v[tid + j * 512] = g0[tid + j * 512];
        s1v[tid + j * 512] = g1[tid + j * 512];
    }
    if (tid < NPATH / 2)   // 4 KiB of metadata as float4
        reinterpret_cast<float4*>(smeta)[tid] =
            reinterpret_cast<const float4*>(ws->meta)[tid];
    if (tid < NSEG + 1) sseg[tid] = ws->segstart[tid];
    if (tid < NW + 1)   ssplit[tid] = ws->wsplit[tid];
    __syncthreads();

    const int wave = tid >> 6;
    const int lane = tid & 63;
    const int sBeg = ssplit[wave];
    const int sEnd = ssplit[wave + 1];

    const float2* s0p = reinterpret_cast<const float2*>(lds0);
    const float2* s1p = reinterpret_cast<const float2*>(lds1);
    float* outrow = out + (size_t)b * ROW;

    for (int s = sBeg; s < sEnd; ++s) {
        const int jb = sseg[s];
        const int je = sseg[s + 1];
        float ax = 0.f, ay = 0.f, bx = 0.f, by = 0.f;
        int j = jb;
        for (; j + 3 < je; j += 4) {
            const Meta m0 = smeta[j];
            const Meta m1 = smeta[j + 1];
            const Meta m2 = smeta[j + 2];
            const Meta m3 = smeta[j + 3];
            const float2 u0 = s0p[(m0.pp & 0xffffu) * (U / 2) + lane];
            const float2 w0 = s1p[(m0.pp >> 16)    * (U / 2) + lane];
            const float2 u1 = s0p[(m1.pp & 0xffffu) * (U / 2) + lane];
            const float2 w1 = s1p[(m1.pp >> 16)    * (U / 2) + lane];
            const float2 u2 = s0p[(m2.pp & 0xffffu) * (U / 2) + lane];
            const float2 w2 = s1p[(m2.pp >> 16)    * (U / 2) + lane];
            const float2 u3 = s0p[(m3.pp & 0xffffu) * (U / 2) + lane];
            const float2 w3 = s1p[(m3.pp >> 16)    * (U / 2) + lane];
            ax += m0.c * u0.x * w0.x;  ay += m0.c * u0.y * w0.y;
            bx += m1.c * u1.x * w1.x;  by += m1.c * u1.y * w1.y;
            ax += m2.c * u2.x * w2.x;  ay += m2.c * u2.y * w2.y;
            bx += m3.c * u3.x * w3.x;  by += m3.c * u3.y * w3.y;
        }
        for (; j < je; ++j) {
            const Meta m = smeta[j];
            const float2 u = s0p[(m.pp & 0xffffu) * (U / 2) + lane];
            const float2 w = s1p[(m.pp >> 16)    * (U / 2) + lane];
            ax += m.c * u.x * w.x;
            ay += m.c * u.y * w.y;
        }
        float2 o; o.x = ax + bx; o.y = ay + by;
        reinterpret_cast<float2*>(outrow + s * U)[lane] = o;
    }
}

extern "C" void kernel_launch(void* const* d_in, const int* in_sizes, int n_in,
                              void* d_out, int out_size, void* d_ws, size_t ws_size,
                              hipStream_t stream) {
    const float* x0     = (const float*)d_in[0];
    const float* x1     = (const float*)d_in[1];
    const float* coeffs = (const float*)d_in[2];
    const int*   p0     = (const int*)d_in[3];
    const int*   p1     = (const int*)d_in[4];
    const int*   pout   = (const int*)d_in[5];
    float* out = (float*)d_out;
    WS* ws = (WS*)d_ws;

    build_csr<<<1, 512, 0, stream>>>(coeffs, p0, p1, pout, ws);
    tp_kernel<<<2048, 512, 0, stream>>>(x0, x1, ws, out);
}

// Round 4
// 36.400 us; speedup vs baseline: 4.4070x; 1.0459x over previous
//
#include <hip/hip_runtime.h>

#define U 128
#define NSEG 32
#define NPATH 512
#define ROW (NSEG * U)   // 4096 floats per batch row
#define NW 8             // waves per tp block (512 threads)

// Path metadata, grouped (order-preserving) by pout.
struct Meta { unsigned pp; float c; };   // pp = p0 | (p1 << 16)
struct WS {
    Meta meta[NPATH];        // 4096 B
    int  segstart[NSEG + 1]; // CSR boundaries into meta[]
    int  wsplit[NW + 1];     // segment-boundary split per wave
};

// One block, 512 threads: thread k owns path k. Deterministic parallel
// counting-sort by pout (original-k order preserved within each segment).
__global__ __launch_bounds__(512) void build_csr(const float* __restrict__ coeffs,
                                                 const int* __restrict__ p0,
                                                 const int* __restrict__ p1,
                                                 const int* __restrict__ pout,
                                                 WS* __restrict__ ws) {
    __shared__ int wcnt[NPATH / 64][NSEG];   // per-wave per-segment counts
    __shared__ int wpre[NPATH / 64][NSEG];   // prefix over earlier waves
    __shared__ int sseg[NSEG + 1];
    __shared__ int stot[NSEG];

    const int k    = threadIdx.x;
    const int lane = k & 63;
    const int wave = k >> 6;

    const int   po = pout[k];
    const int   a0 = p0[k];
    const int   a1 = p1[k];
    const float c  = coeffs[k];

    // rank within wave + per-wave counts, via 32 ballots
    const unsigned long long lt = (1ull << lane) - 1ull;
    int rank = 0;
    #pragma unroll
    for (int s = 0; s < NSEG; ++s) {
        unsigned long long m = __ballot(po == s);
        if (po == s)  rank = (int)__popcll(m & lt);
        if (lane == s) wcnt[wave][s] = (int)__popcll(m);
    }
    __syncthreads();

    // per-segment: prefix over waves + totals (threads 0..31)
    if (k < NSEG) {
        int tot = 0;
        #pragma unroll
        for (int w = 0; w < NPATH / 64; ++w) { wpre[w][k] = tot; tot += wcnt[w][k]; }
        stot[k] = tot;
    }
    __syncthreads();

    // exclusive scan of totals over segments (wave 0)
    if (k < 64) {
        int v = (k < NSEG) ? stot[k] : 0;
        int inc = v;
        #pragma unroll
        for (int d = 1; d < 64; d <<= 1) {
            int t = __shfl_up(inc, d, 64);
            if (k >= d) inc += t;
        }
        int excl = inc - v;
        if (k < NSEG) sseg[k] = excl;
        if (k == NSEG - 1) sseg[NSEG] = excl + v;
    }
    __syncthreads();

    // scatter (deterministic position)
    {
        Meta m;
        m.pp = (unsigned)a0 | ((unsigned)a1 << 16);
        m.c  = c;
        ws->meta[sseg[po] + wpre[wave][po] + rank] = m;
    }
    if (k <= NSEG) ws->segstart[k] = sseg[k];

    // balanced NW-way split boundaries (wave 0); argmin |segstart - target|
    if (k < 64) {
        #pragma unroll
        for (int w = 1; w < NW; ++w) {
            const int target = (NPATH * w) / NW;
            int key;
            if (k <= NSEG) {
                int d = sseg[k] - target; if (d < 0) d = -d;
                key = (d << 6) | k;
            } else key = 0x7fffffff;
            #pragma unroll
            for (int m = 32; m >= 1; m >>= 1) {
                int o = __shfl_xor(key, m, 64);
                key = (o < key) ? o : key;
            }
            if (k == 0) ws->wsplit[w] = key & 63;
        }
        if (k == 0) { ws->wsplit[0] = 0; ws->wsplit[NW] = NSEG; }
    }
}

// One block (512 threads, 8 waves) per batch row. Pair scheme: lanes 0-31
// process path j, lanes 32-63 path j+1 (same output segment), each lane
// covering 4 u-elements via ds_read_b128. Segment finish: cross-half
// shfl_xor reduce + float4 store from the low half.
__global__ __launch_bounds__(512) void tp_kernel(const float* __restrict__ x0,
                                                 const float* __restrict__ x1,
                                                 const WS* __restrict__ ws,
                                                 float* __restrict__ out) {
    __shared__ float lds0[ROW];
    __shared__ float lds1[ROW];
    __shared__ Meta  smeta[NPATH];
    __shared__ int   sseg[NSEG + 1];
    __shared__ int   ssplit[NW + 1];

    const int b   = blockIdx.x;
    const int tid = threadIdx.x;

    // stage rows (coalesced float4)
    const float4* g0 = reinterpret_cast<const float4*>(x0 + (size_t)b * ROW);
    const float4* g1 = reinterpret_cast<const float4*>(x1 + (size_t)b * ROW);
    float4* s0v = reinterpret_cast<float4*>(lds0);
    float4* s1v = reinterpret_cast<float4*>(lds1);
    #pragma unroll
    for (int j = 0; j < (ROW / 4) / 512; ++j) {   // 2 iters each
        s0v[tid + j * 512] = g0[tid + j * 512];
        s1v[tid + j * 512] = g1[tid + j * 512];
    }
    if (tid < NPATH / 2)   // 4 KiB of metadata as float4
        reinterpret_cast<float4*>(smeta)[tid] =
            reinterpret_cast<const float4*>(ws->meta)[tid];
    if (tid < NSEG + 1) sseg[tid] = ws->segstart[tid];
    if (tid < NW + 1)   ssplit[tid] = ws->wsplit[tid];
    __syncthreads();

    const int wave = tid >> 6;
    const int lane = tid & 63;
    const int half = lane >> 5;   // 0: low 32 lanes, 1: high 32 lanes
    const int sub  = lane & 31;   // float4 slot within a segment

    const int sBeg = __builtin_amdgcn_readfirstlane(ssplit[wave]);
    const int sEnd = __builtin_amdgcn_readfirstlane(ssplit[wave + 1]);

    const float4* s0q = reinterpret_cast<const float4*>(lds0);
    const float4* s1q = reinterpret_cast<const float4*>(lds1);
    float* outrow = out + (size_t)b * ROW;

    for (int s = sBeg; s < sEnd; ++s) {
        const int jb = __builtin_amdgcn_readfirstlane(sseg[s]);
        const int je = __builtin_amdgcn_readfirstlane(sseg[s + 1]);
        float4 acc0 = make_float4(0.f, 0.f, 0.f, 0.f);
        float4 acc1 = make_float4(0.f, 0.f, 0.f, 0.f);
        int j = jb;
        for (; j + 3 < je; j += 4) {   // 4 paths in flight (2 pair-groups)
            const Meta mA = smeta[j + half];
            const Meta mB = smeta[j + 2 + half];
            const float4 uA = s0q[(mA.pp & 0xffffu) * (U / 4) + sub];
            const float4 wA = s1q[(mA.pp >> 16)     * (U / 4) + sub];
            const float4 uB = s0q[(mB.pp & 0xffffu) * (U / 4) + sub];
            const float4 wB = s1q[(mB.pp >> 16)     * (U / 4) + sub];
            acc0.x += mA.c * uA.x * wA.x;
            acc0.y += mA.c * uA.y * wA.y;
            acc0.z += mA.c * uA.z * wA.z;
            acc0.w += mA.c * uA.w * wA.w;
            acc1.x += mB.c * uB.x * wB.x;
            acc1.y += mB.c * uB.y * wB.y;
            acc1.z += mB.c * uB.z * wB.z;
            acc1.w += mB.c * uB.w * wB.w;
        }
        for (; j + 1 < je; j += 2) {   // 2 paths (1 pair-group)
            const Meta m = smeta[j + half];
            const float4 u = s0q[(m.pp & 0xffffu) * (U / 4) + sub];
            const float4 w = s1q[(m.pp >> 16)     * (U / 4) + sub];
            acc0.x += m.c * u.x * w.x;
            acc0.y += m.c * u.y * w.y;
            acc0.z += m.c * u.z * w.z;
            acc0.w += m.c * u.w * w.w;
        }
        if (j < je) {                  // odd tail: both halves read it, upper zeroed
            const Meta m = smeta[j];
            const float cc = (half == 0) ? m.c : 0.f;
            const float4 u = s0q[(m.pp & 0xffffu) * (U / 4) + sub];
            const float4 w = s1q[(m.pp >> 16)     * (U / 4) + sub];
            acc0.x += cc * u.x * w.x;
            acc0.y += cc * u.y * w.y;
            acc0.z += cc * u.z * w.z;
            acc0.w += cc * u.w * w.w;
        }
        float4 a;
        a.x = acc0.x + acc1.x;
        a.y = acc0.y + acc1.y;
        a.z = acc0.z + acc1.z;
        a.w = acc0.w + acc1.w;
        a.x += __shfl_xor(a.x, 32, 64);
        a.y += __shfl_xor(a.y, 32, 64);
        a.z += __shfl_xor(a.z, 32, 64);
        a.w += __shfl_xor(a.w, 32, 64);
        if (half == 0)
            reinterpret_cast<float4*>(outrow + s * U)[sub] = a;
    }
}

extern "C" void kernel_launch(void* const* d_in, const int* in_sizes, int n_in,
                              void* d_out, int out_size, void* d_ws, size_t ws_size,
                              hipStream_t stream) {
    const float* x0     = (const float*)d_in[0];
    const float* x1     = (const float*)d_in[1];
    const float* coeffs = (const float*)d_in[2];
    const int*   p0     = (const int*)d_in[3];
    const int*   p1     = (const int*)d_in[4];
    const int*   pout   = (const int*)d_in[5];
    float* out = (float*)d_out;
    WS* ws = (WS*)d_ws;

    build_csr<<<1, 512, 0, stream>>>(coeffs, p0, p1, pout, ws);
    tp_kernel<<<2048, 512, 0, stream>>>(x0, x1, ws, out);
}